// Round 11
// baseline (145.616 us; speedup 1.0000x reference)
//
#include <hip/hip_runtime.h>

#define S_LEN  4096
#define DM     6
#define NLAYER 4
#define NFF    64
#define HALO   8
#define TPB    64                 // one wave per block
#define PPL    4                  // positions per lane
#define OUT_PER_WAVE 240          // 256 held - 2*HALO
#define WBX    18                 // waves (blocks.x) per batch: ceil(4096/240)

typedef float    vf4 __attribute__((ext_vector_type(4)));
typedef _Float16 vh2 __attribute__((ext_vector_type(2)));
typedef _Float16 vh4 __attribute__((ext_vector_type(4)));

// wave-private LDS: X = 256 tight 16B f16 rows; Ypk = f16-pair rows [3][260]
#define XSZ      (256*16)            // 4096 B
#define YSTRIDE  260                 // dwords (mult of 4 for b128 readback)
#define YSZ      (3*YSTRIDE*4)       // 3120 B
#define LDS_TOT  (XSZ + YSZ)         // 7216 B

__device__ __forceinline__ vf4 splat4(float s){ vf4 r; r.x=s;r.y=s;r.z=s;r.w=s; return r; }
__device__ __forceinline__ unsigned pkh(float a, float b){
    return __builtin_bit_cast(unsigned, __builtin_amdgcn_cvt_pkrtz(a, b));
}
__device__ __forceinline__ vh2 bch2(unsigned u){ return __builtin_bit_cast(vh2, u); }

// LayerNorm over 6 dims, 4 positions packed per vf4.
__device__ __forceinline__ void ln6v4(vf4* v, const float* __restrict__ w,
                                      const float* __restrict__ b) {
    vf4 mu = (((v[0]+v[1])+(v[2]+v[3]))+(v[4]+v[5])) * (1.0f/6.0f);
    vf4 var = splat4(0.0f);
#pragma unroll
    for (int d = 0; d < DM; ++d) { vf4 dd = v[d]-mu; var = __builtin_elementwise_fma(dd, dd, var); }
    vf4 a = var * (1.0f/6.0f) + splat4(1e-6f);
    vf4 r; r.x=rsqrtf(a.x); r.y=rsqrtf(a.y); r.z=rsqrtf(a.z); r.w=rsqrtf(a.w);
#pragma unroll
    for (int d = 0; d < DM; ++d)
        v[d] = __builtin_elementwise_fma((v[d]-mu)*r, splat4(w[d]), splat4(b[d]));
}

__global__ __launch_bounds__(TPB)
void decoder_fused(const float* __restrict__ x_batch,
                   const float* __restrict__ dec_ln_w, const float* __restrict__ dec_ln_b,
                   const float* __restrict__ qw, const float* __restrict__ qb,
                   const float* __restrict__ kw, const float* __restrict__ kb,
                   const float* __restrict__ vw, const float* __restrict__ vb,
                   const float* __restrict__ mha_ln_w, const float* __restrict__ mha_ln_b,
                   const float* __restrict__ ffn_w1, const float* __restrict__ ffn_b1,
                   const float* __restrict__ ffn_w2, const float* __restrict__ ffn_b2,
                   const float* __restrict__ ffn_ln_w, const float* __restrict__ ffn_ln_b,
                   float* __restrict__ out) {
    const int lane = threadIdx.x;
    const int w    = blockIdx.x;
    const int b    = blockIdx.y;
    const int p0   = w * OUT_PER_WAVE - HALO + PPL*lane;   // first of 4 positions
    const int c    = lane & 15, g = lane >> 4;

    __shared__ __align__(16) char smem[LDS_TOT];
    char* Xb = smem;
    char* Yb = smem + XSZ;

    vf4 x4[DM];   // x4[d] = {pos p0, p0+1, p0+2, p0+3}
    if (p0 >= 0 && p0 + PPL <= S_LEN) {
        const float4* s = reinterpret_cast<const float4*>(x_batch + ((size_t)b*S_LEN + p0)*DM);
        float4 a0=s[0],a1=s[1],a2=s[2],a3=s[3],a4=s[4],a5=s[5];
        x4[0] = (vf4){a0.x, a1.z, a3.x, a4.z};
        x4[1] = (vf4){a0.y, a1.w, a3.y, a4.w};
        x4[2] = (vf4){a0.z, a2.x, a3.z, a5.x};
        x4[3] = (vf4){a0.w, a2.y, a3.w, a5.y};
        x4[4] = (vf4){a1.x, a2.z, a4.x, a5.z};
        x4[5] = (vf4){a1.y, a2.w, a4.y, a5.w};
    } else {
        float tmp[PPL][DM];
#pragma unroll
        for (int s = 0; s < PPL; ++s) {
            const int pc = min(max(p0 + s, 0), S_LEN-1);
            const float2* f2 = reinterpret_cast<const float2*>(x_batch + ((size_t)b*S_LEN + pc)*DM);
            float2 u0 = f2[0], u1 = f2[1], u2 = f2[2];
            tmp[s][0]=u0.x; tmp[s][1]=u0.y; tmp[s][2]=u1.x;
            tmp[s][3]=u1.y; tmp[s][4]=u2.x; tmp[s][5]=u2.y;
        }
#pragma unroll
        for (int d = 0; d < DM; ++d)
            x4[d] = (vf4){tmp[0][d], tmp[1][d], tmp[2][d], tmp[3][d]};
    }

    ln6v4(x4, dec_ln_w, dec_ln_b);

#pragma unroll 1
    for (int li = 0; li < NLAYER; ++li) {
        // ---- build this layer's FFN MFMA fragments in-register (L2-resident) ----
        vh4 w1f[4], w2f[4]; vf4 b1f[4];
#pragma unroll
        for (int mt = 0; mt < 4; ++mt) {
            const int f = mt*16 + c;
            float4 a = make_float4(0.f, 0.f, 0.f, 0.f);
            if (g == 0) {
                float2 u = *reinterpret_cast<const float2*>(ffn_w1 + li*NFF*DM + f*DM);
                float2 v = *reinterpret_cast<const float2*>(ffn_w1 + li*NFF*DM + f*DM + 2);
                a = make_float4(u.x, u.y, v.x, v.y);
            } else if (g == 1) {
                float2 u = *reinterpret_cast<const float2*>(ffn_w1 + li*NFF*DM + f*DM + 4);
                a = make_float4(u.x, u.y, 0.f, 0.f);
            }
            uint2 ua = make_uint2(pkh(a.x, a.y), pkh(a.z, a.w));
            w1f[mt] = __builtin_bit_cast(vh4, ua);

            float4 wv = make_float4(0.f, 0.f, 0.f, 0.f);
            if (c < DM)
                wv = *reinterpret_cast<const float4*>(ffn_w2 + li*DM*NFF + c*NFF + mt*16 + g*4);
            uint2 uw = make_uint2(pkh(wv.x, wv.y), pkh(wv.z, wv.w));
            w2f[mt] = __builtin_bit_cast(vh4, uw);

            float4 bb = *reinterpret_cast<const float4*>(ffn_b1 + li*NFF + mt*16 + g*4);
            b1f[mt] = (vf4){bb.x, bb.y, bb.z, bb.w};
        }

        // -------- two mha blocks: f16-packed edge shuffles (6 DS ops/stage) --------
#pragma unroll 1
        for (int ai = 0; ai < 2; ++ai) {
            const int base = (li*2 + ai) * DM;
            // pack slot3 (for up) and slot0 (for down), 2 dims per dword
            unsigned s3a = pkh(x4[0].w, x4[1].w), s3b = pkh(x4[2].w, x4[3].w), s3c = pkh(x4[4].w, x4[5].w);
            unsigned s0a = pkh(x4[0].x, x4[1].x), s0b = pkh(x4[2].x, x4[3].x), s0c = pkh(x4[4].x, x4[5].x);
            unsigned ua = __shfl_up((int)s3a, 1), ub = __shfl_up((int)s3b, 1), uc = __shfl_up((int)s3c, 1);
            unsigned da = __shfl_down((int)s0a, 1), db = __shfl_down((int)s0b, 1), dc = __shfl_down((int)s0c, 1);
            float pm[DM], pp[DM];
            { vh2 h; h=bch2(ua); pm[0]=(float)h.x; pm[1]=(float)h.y;
                     h=bch2(ub); pm[2]=(float)h.x; pm[3]=(float)h.y;
                     h=bch2(uc); pm[4]=(float)h.x; pm[5]=(float)h.y;
                     h=bch2(da); pp[0]=(float)h.x; pp[1]=(float)h.y;
                     h=bch2(db); pp[2]=(float)h.x; pp[3]=(float)h.y;
                     h=bch2(dc); pp[4]=(float)h.x; pp[5]=(float)h.y; }
            const bool first = (p0 <= 0);
            const bool last  = (p0 + PPL - 1 >= S_LEN - 1);
#pragma unroll
            for (int d = 0; d < DM; ++d) {
                float prevv = first ? x4[d].x : pm[d];
                float nextv = last  ? x4[d].w : pp[d];
                vf4 xm = (vf4){prevv,   x4[d].x, x4[d].y, x4[d].z};
                vf4 xp = (vf4){x4[d].y, x4[d].z, x4[d].w, nextv};
                vf4 q = __builtin_elementwise_fma(x4[d], splat4(qw[base+d]), splat4(qb[base+d]));
                vf4 k = __builtin_elementwise_fma(xm,    splat4(kw[base+d]), splat4(kb[base+d]));
                vf4 v = __builtin_elementwise_fma(xp,    splat4(vw[base+d]), splat4(vb[base+d]));
                vf4 teo = __builtin_elementwise_fma(q, q, -(k*v));
                x4[d] = __builtin_elementwise_fma(teo, splat4(1.0f/(float)S_LEN), x4[d]);
            }
            ln6v4(x4, mha_ln_w + base, mha_ln_b + base);
        }

        // -------- FFN via per-wave MFMA: Ht = W1·Xt, Ypk = pk-f16(W2·relu(Ht+b1)) --------
        {
            // stage X: lane's 4 positions as tight 16B rows (k=6,7 pad in-store)
            {
                char* r0 = Xb + lane*64;
                *(uint4*)(r0)    = make_uint4(pkh(x4[0].x,x4[1].x), pkh(x4[2].x,x4[3].x), pkh(x4[4].x,x4[5].x), 0u);
                *(uint4*)(r0+16) = make_uint4(pkh(x4[0].y,x4[1].y), pkh(x4[2].y,x4[3].y), pkh(x4[4].y,x4[5].y), 0u);
                *(uint4*)(r0+32) = make_uint4(pkh(x4[0].z,x4[1].z), pkh(x4[2].z,x4[3].z), pkh(x4[4].z,x4[5].z), 0u);
                *(uint4*)(r0+48) = make_uint4(pkh(x4[0].w,x4[1].w), pkh(x4[2].w,x4[3].w), pkh(x4[4].w,x4[5].w), 0u);
            }
            // B-frags: k=g*4..g*4+3; g<2 from LDS (zero pad covers k=6,7); g>=2 -> zero.
            vh4 bfrag[16];
#pragma unroll
            for (int t = 0; t < 16; ++t) {
                vh4 v = *(const vh4*)(Xb + (16*t + c)*16 + (g&1)*8);
                if (g >= 2) v = (vh4)(_Float16)0;
                bfrag[t] = v;
            }

#pragma unroll
            for (int t = 0; t < 16; ++t) {
                vh4 hb[4];
#pragma unroll
                for (int ft = 0; ft < 4; ++ft) {
                    vf4 hc = __builtin_amdgcn_mfma_f32_16x16x16f16(w1f[ft], bfrag[t], b1f[ft], 0, 0, 0);
                    uint2 u = make_uint2(pkh(hc.x,hc.y), pkh(hc.z,hc.w));
                    vh4 hraw = __builtin_bit_cast(vh4, u);
                    hb[ft] = __builtin_elementwise_max(hraw, (vh4)(_Float16)0);
                }
                vf4 yacc; yacc.x=0.f; yacc.y=0.f; yacc.z=0.f; yacc.w=0.f;
#pragma unroll
                for (int ks = 0; ks < 4; ++ks)
                    yacc = __builtin_amdgcn_mfma_f32_16x16x16f16(w2f[ks], hb[ks], yacc, 0, 0, 0);
                // pack dim-pairs: g=0 regs->rows0-3 => prow0=(d0,d1),prow1=(d2,d3);
                //                 g=1 regs0,1->rows4,5 => prow2=(d4,d5); rows6,7 dropped
                const int col = 16*t + c;
                unsigned* yp = (unsigned*)Yb;
                if (lane < 32)
                    yp[(g*2)*YSTRIDE + col] = pkh(yacc.x, yacc.y);   // prow0 or prow2
                if (lane < 16)
                    yp[1*YSTRIDE + col] = pkh(yacc.z, yacc.w);       // prow1
            }
            const float* b2 = ffn_b2 + li*DM;
#pragma unroll
            for (int pr = 0; pr < 3; ++pr) {
                uint4 u = *(const uint4*)((unsigned*)Yb + pr*YSTRIDE + 4*lane);
                vh2 h0 = bch2(u.x), h1 = bch2(u.y), h2 = bch2(u.z), h3 = bch2(u.w);
                vf4 ylo = (vf4){(float)h0.x, (float)h1.x, (float)h2.x, (float)h3.x};
                vf4 yhi = (vf4){(float)h0.y, (float)h1.y, (float)h2.y, (float)h3.y};
                x4[2*pr]   = x4[2*pr]   + splat4(b2[2*pr])   + ylo;
                x4[2*pr+1] = x4[2*pr+1] + splat4(b2[2*pr+1]) + yhi;
            }
            ln6v4(x4, ffn_ln_w + li*DM, ffn_ln_b + li*DM);
        }
    }

    // lanes 2..61 hold the wave's 240 valid output positions
    if (lane >= 2 && lane < 62 && p0 < S_LEN) {
        float4* dst = reinterpret_cast<float4*>(out + ((size_t)b*S_LEN + p0)*DM);
        dst[0] = make_float4(x4[0].x, x4[1].x, x4[2].x, x4[3].x);
        dst[1] = make_float4(x4[4].x, x4[5].x, x4[0].y, x4[1].y);
        dst[2] = make_float4(x4[2].y, x4[3].y, x4[4].y, x4[5].y);
        dst[3] = make_float4(x4[0].z, x4[1].z, x4[2].z, x4[3].z);
        dst[4] = make_float4(x4[4].z, x4[5].z, x4[0].w, x4[1].w);
        dst[5] = make_float4(x4[2].w, x4[3].w, x4[4].w, x4[5].w);
    }
}

extern "C" void kernel_launch(void* const* d_in, const int* in_sizes, int n_in,
                              void* d_out, int out_size, void* d_ws, size_t ws_size,
                              hipStream_t stream) {
    const float* x_batch  = (const float*)d_in[0];
    // d_in[1] enc_output: unused by the reference
    const float* dec_ln_w = (const float*)d_in[2];
    const float* dec_ln_b = (const float*)d_in[3];
    const float* qw       = (const float*)d_in[4];
    const float* qb       = (const float*)d_in[5];
    const float* kw       = (const float*)d_in[6];
    const float* kb       = (const float*)d_in[7];
    const float* vw       = (const float*)d_in[8];
    const float* vb       = (const float*)d_in[9];
    // d_in[10..11] ln1_w/ln1_b: dead (softmax of a seq-constant)
    const float* mha_ln_w = (const float*)d_in[12];
    const float* mha_ln_b = (const float*)d_in[13];
    const float* ffn_w1   = (const float*)d_in[14];
    const float* ffn_b1   = (const float*)d_in[15];
    const float* ffn_w2   = (const float*)d_in[16];
    const float* ffn_b2   = (const float*)d_in[17];
    const float* ffn_ln_w = (const float*)d_in[18];
    const float* ffn_ln_b = (const float*)d_in[19];
    float* out = (float*)d_out;

    const int B = in_sizes[0] / (S_LEN * DM);   // 128
    dim3 grid(WBX, B);
    decoder_fused<<<grid, TPB, 0, stream>>>(
        x_batch, dec_ln_w, dec_ln_b, qw, qb, kw, kb, vw, vb,
        mha_ln_w, mha_ln_b, ffn_w1, ffn_b1, ffn_w2, ffn_b2,
        ffn_ln_w, ffn_ln_b, out);
}

// Round 12
// 140.090 us; speedup vs baseline: 1.0394x; 1.0394x over previous
//
#include <hip/hip_runtime.h>

#define S_LEN  4096
#define DM     6
#define NLAYER 4
#define NFF    64
#define HALO   8
#define TPB    256
#define OUT_PER_WAVE 112              // wave holds 128 positions, outputs 112
#define BLK_X 10                      // ceil(37 waves / 4 per block)

typedef float    vf2 __attribute__((ext_vector_type(2)));
typedef float    vf4 __attribute__((ext_vector_type(4)));
typedef _Float16 vh4 __attribute__((ext_vector_type(4)));

// wave-private LDS:
//  X: 128 tight 16-B rows [pk01,pk23,pk45,0]; k=6,7 pad stored, k=8..15
//     zeroed at the destination fragment (g>=2).
//  Yt: f32 [6][130] readback (rows 6,7 never read -> dropped)
#define XSZ (128*16)             // 2048 B
#define YSTRIDE 130              // dwords
#define YSZ (6*YSTRIDE*4)        // 3120 B
#define WAVE_LDS (XSZ + YSZ)     // 5168 B -> 20672 B/block -> 7 blocks/CU by LDS

__device__ __forceinline__ vf2 splat2(float s){ vf2 r; r.x = s; r.y = s; return r; }
__device__ __forceinline__ unsigned pkh(float a, float b){
    return __builtin_bit_cast(unsigned, __builtin_amdgcn_cvt_pkrtz(a, b));
}

// LayerNorm over 6 dims, two seq positions packed per vf2.
__device__ __forceinline__ void ln6v(vf2* v, const float* __restrict__ w,
                                     const float* __restrict__ b) {
    vf2 mu = (((v[0]+v[1])+(v[2]+v[3]))+(v[4]+v[5])) * (1.0f/6.0f);
    vf2 var = splat2(0.0f);
#pragma unroll
    for (int d = 0; d < DM; ++d) { vf2 dd = v[d]-mu; var = __builtin_elementwise_fma(dd, dd, var); }
    vf2 a = var * (1.0f/6.0f) + splat2(1e-6f);
    vf2 r; r.x = rsqrtf(a.x); r.y = rsqrtf(a.y);
#pragma unroll
    for (int d = 0; d < DM; ++d)
        v[d] = __builtin_elementwise_fma((v[d]-mu)*r, splat2(w[d]), splat2(b[d]));
}

__global__ __launch_bounds__(TPB)
void decoder_fused(const float* __restrict__ x_batch,
                   const float* __restrict__ dec_ln_w, const float* __restrict__ dec_ln_b,
                   const float* __restrict__ qw, const float* __restrict__ qb,
                   const float* __restrict__ kw, const float* __restrict__ kb,
                   const float* __restrict__ vw, const float* __restrict__ vb,
                   const float* __restrict__ mha_ln_w, const float* __restrict__ mha_ln_b,
                   const float* __restrict__ ffn_w1, const float* __restrict__ ffn_b1,
                   const float* __restrict__ ffn_w2, const float* __restrict__ ffn_b2,
                   const float* __restrict__ ffn_ln_w, const float* __restrict__ ffn_ln_b,
                   float* __restrict__ out) {
    const int lane = threadIdx.x & 63;
    const int wid  = threadIdx.x >> 6;
    const int w    = blockIdx.x * (TPB/64) + wid;                 // wave index in batch
    const int b    = blockIdx.y;
    const int p    = w * OUT_PER_WAVE - HALO + 2*lane;            // even seq position
    const int c    = lane & 15, g = lane >> 4;

    __shared__ __align__(16) char smem[(TPB/64) * WAVE_LDS];
    char* wbase = smem + wid * WAVE_LDS;
    char* Xb = wbase;
    char* Yb = wbase + XSZ;

    vf2 x2[DM];   // .x = pos p, .y = pos p+1
    if (p >= 0 && p + 1 < S_LEN) {
        const float4* s = reinterpret_cast<const float4*>(x_batch + ((size_t)b*S_LEN + p)*DM);
        float4 a0 = s[0], a1 = s[1], a2 = s[2];
        x2[0].x=a0.x; x2[1].x=a0.y; x2[2].x=a0.z; x2[3].x=a0.w; x2[4].x=a1.x; x2[5].x=a1.y;
        x2[0].y=a1.z; x2[1].y=a1.w; x2[2].y=a2.x; x2[3].y=a2.y; x2[4].y=a2.z; x2[5].y=a2.w;
    } else {
        const int pc = min(max(p, 0), S_LEN-1);
        const float2* s = reinterpret_cast<const float2*>(x_batch + ((size_t)b*S_LEN + pc)*DM);
        float2 a0 = s[0], a1 = s[1], a2 = s[2];
        x2[0] = splat2(a0.x); x2[1] = splat2(a0.y); x2[2] = splat2(a1.x);
        x2[3] = splat2(a1.y); x2[4] = splat2(a2.x); x2[5] = splat2(a2.y);
    }

    ln6v(x2, dec_ln_w, dec_ln_b);

#pragma unroll 1
    for (int li = 0; li < NLAYER; ++li) {
        // ---- build this layer's FFN MFMA fragments in-register (L2-resident) ----
        // w1f[mt]: A-frag of W1, A[m=f=mt*16+c][k=d=g*4+j]; d>=6 -> 0
        // w2f[ks]: A-frag of W2, A[m=d=c][k=ks*16+g*4+j]; c>=6 -> 0
        vh4 w1f[4], w2f[4]; vf4 b1f[4];
#pragma unroll
        for (int mt = 0; mt < 4; ++mt) {
            const int f = mt*16 + c;
            float4 a = make_float4(0.f, 0.f, 0.f, 0.f);
            if (g == 0) {
                float2 u = *reinterpret_cast<const float2*>(ffn_w1 + li*NFF*DM + f*DM);
                float2 v = *reinterpret_cast<const float2*>(ffn_w1 + li*NFF*DM + f*DM + 2);
                a = make_float4(u.x, u.y, v.x, v.y);
            } else if (g == 1) {
                float2 u = *reinterpret_cast<const float2*>(ffn_w1 + li*NFF*DM + f*DM + 4);
                a = make_float4(u.x, u.y, 0.f, 0.f);
            }
            uint2 ua = make_uint2(pkh(a.x, a.y), pkh(a.z, a.w));
            w1f[mt] = __builtin_bit_cast(vh4, ua);

            float4 wv = make_float4(0.f, 0.f, 0.f, 0.f);
            if (c < DM)
                wv = *reinterpret_cast<const float4*>(ffn_w2 + li*DM*NFF + c*NFF + mt*16 + g*4);
            uint2 uw = make_uint2(pkh(wv.x, wv.y), pkh(wv.z, wv.w));
            w2f[mt] = __builtin_bit_cast(vh4, uw);

            float4 bb = *reinterpret_cast<const float4*>(ffn_b1 + li*NFF + mt*16 + g*4);
            vf4 bv; bv.x=bb.x; bv.y=bb.y; bv.z=bb.z; bv.w=bb.w;
            b1f[mt] = bv;
        }

        // -------- two mha blocks: barrier-free neighbor exchange via shuffles --------
#pragma unroll 1
        for (int ai = 0; ai < 2; ++ai) {
            const int base = (li*2 + ai) * DM;
            vf2 xm[DM], xp[DM];
#pragma unroll
            for (int d = 0; d < DM; ++d) {
                float up = __shfl_up (x2[d].y, 1);   // pos p-1
                float dn = __shfl_down(x2[d].x, 1);  // pos p+2
                xm[d].x = (p <= 0) ? x2[d].x : up;
                xm[d].y = x2[d].x;
                xp[d].x = x2[d].y;
                xp[d].y = (p + 1 >= S_LEN - 1) ? x2[d].y : dn;
            }
#pragma unroll
            for (int d = 0; d < DM; ++d) {
                vf2 q = __builtin_elementwise_fma(x2[d], splat2(qw[base+d]), splat2(qb[base+d]));
                vf2 k = __builtin_elementwise_fma(xm[d], splat2(kw[base+d]), splat2(kb[base+d]));
                vf2 v = __builtin_elementwise_fma(xp[d], splat2(vw[base+d]), splat2(vb[base+d]));
                vf2 teo = __builtin_elementwise_fma(q, q, -(k*v));
                x2[d] = __builtin_elementwise_fma(teo, splat2(1.0f/(float)S_LEN), x2[d]);
            }
            ln6v(x2, mha_ln_w + base, mha_ln_b + base);
        }

        // -------- FFN via per-wave MFMA: Ht = W1·Xt, Yt = W2·relu(Ht+b1) --------
        {
            // stage X: lane's two positions as tight 16B rows (k=6,7 pad in-store)
            {
                char* r0 = Xb + lane*32;
                *(uint4*)r0      = make_uint4(pkh(x2[0].x,x2[1].x), pkh(x2[2].x,x2[3].x),
                                              pkh(x2[4].x,x2[5].x), 0u);
                *(uint4*)(r0+16) = make_uint4(pkh(x2[0].y,x2[1].y), pkh(x2[2].y,x2[3].y),
                                              pkh(x2[4].y,x2[5].y), 0u);
            }
            // B-frags: k = g*4..g*4+3. g=0 -> dwords 0,1; g=1 -> dwords 2,3
            // (incl. stored zero pad); g>=2 -> k in 8..15 must be ZERO: mask at dest.
            vh4 bfrag[8];
#pragma unroll
            for (int t = 0; t < 8; ++t) {
                vh4 v = *(const vh4*)(Xb + (16*t + c)*16 + (g&1)*8);
                if (g >= 2) v = (vh4)(_Float16)0;
                bfrag[t] = v;
            }

#pragma unroll
            for (int t = 0; t < 8; ++t) {
                vh4 hb[4];
#pragma unroll
                for (int ft = 0; ft < 4; ++ft) {
                    vf4 hc = __builtin_amdgcn_mfma_f32_16x16x16f16(w1f[ft], bfrag[t], b1f[ft], 0, 0, 0);
                    uint2 u = make_uint2(pkh(hc.x,hc.y), pkh(hc.z,hc.w));
                    vh4 hraw = __builtin_bit_cast(vh4, u);
                    vh4 z4 = (vh4)(_Float16)0;
                    hb[ft] = __builtin_elementwise_max(hraw, z4);   // relu in pk-f16
                }
                vf4 yacc; yacc.x=0.f; yacc.y=0.f; yacc.z=0.f; yacc.w=0.f;
#pragma unroll
                for (int ks = 0; ks < 4; ++ks)
                    yacc = __builtin_amdgcn_mfma_f32_16x16x16f16(w2f[ks], hb[ks], yacc, 0, 0, 0);
                int col = 16*t + c;
                float* yp = (float*)Yb;
                if (lane < 32) {                 // rows g*4, g*4+1  (g=1 -> rows 4,5)
                    yp[(g*4+0)*YSTRIDE + col] = yacc.x;
                    yp[(g*4+1)*YSTRIDE + col] = yacc.y;
                }
                if (lane < 16) {                 // rows 2,3 (rows 6,7 dropped)
                    yp[2*YSTRIDE + col] = yacc.z;
                    yp[3*YSTRIDE + col] = yacc.w;
                }
            }
            const float* b2 = ffn_b2 + li*DM;
#pragma unroll
            for (int d = 0; d < DM; ++d) {
                float2 yv = *(const float2*)((float*)Yb + d*YSTRIDE + 2*lane);
                vf2 t2; t2.x = yv.x; t2.y = yv.y;
                x2[d] = x2[d] + splat2(b2[d]) + t2;
            }
            ln6v(x2, ffn_ln_w + li*DM, ffn_ln_b + li*DM);
        }
    }

    // lanes 4..59 hold the wave's 112 valid output positions
    if (lane >= 4 && lane < 60 && p < S_LEN) {
        float4* dst = reinterpret_cast<float4*>(out + ((size_t)b*S_LEN + p)*DM);
        float4 a0, a1, a2;
        a0.x=x2[0].x; a0.y=x2[1].x; a0.z=x2[2].x; a0.w=x2[3].x;
        a1.x=x2[4].x; a1.y=x2[5].x; a1.z=x2[0].y; a1.w=x2[1].y;
        a2.x=x2[2].y; a2.y=x2[3].y; a2.z=x2[4].y; a2.w=x2[5].y;
        dst[0]=a0; dst[1]=a1; dst[2]=a2;
    }
}

extern "C" void kernel_launch(void* const* d_in, const int* in_sizes, int n_in,
                              void* d_out, int out_size, void* d_ws, size_t ws_size,
                              hipStream_t stream) {
    const float* x_batch  = (const float*)d_in[0];
    // d_in[1] enc_output: unused by the reference
    const float* dec_ln_w = (const float*)d_in[2];
    const float* dec_ln_b = (const float*)d_in[3];
    const float* qw       = (const float*)d_in[4];
    const float* qb       = (const float*)d_in[5];
    const float* kw       = (const float*)d_in[6];
    const float* kb       = (const float*)d_in[7];
    const float* vw       = (const float*)d_in[8];
    const float* vb       = (const float*)d_in[9];
    // d_in[10..11] ln1_w/ln1_b: dead (softmax of a seq-constant)
    const float* mha_ln_w = (const float*)d_in[12];
    const float* mha_ln_b = (const float*)d_in[13];
    const float* ffn_w1   = (const float*)d_in[14];
    const float* ffn_b1   = (const float*)d_in[15];
    const float* ffn_w2   = (const float*)d_in[16];
    const float* ffn_b2   = (const float*)d_in[17];
    const float* ffn_ln_w = (const float*)d_in[18];
    const float* ffn_ln_b = (const float*)d_in[19];
    float* out = (float*)d_out;

    const int B = in_sizes[0] / (S_LEN * DM);   // 128
    dim3 grid(BLK_X, B);
    decoder_fused<<<grid, TPB, 0, stream>>>(
        x_batch, dec_ln_w, dec_ln_b, qw, qb, kw, kb, vw, vb,
        mha_ln_w, mha_ln_b, ffn_w1, ffn_b1, ffn_w2, ffn_b2,
        ffn_ln_w, ffn_ln_b, out);
}